// Round 2
// baseline (2243.961 us; speedup 1.0000x reference)
//
#include <hip/hip_runtime.h>
#include <cstdint>

// B=256, C=256, H=W=15, S=8.
constexpr int B_ = 256, C_ = 256, H_ = 15, W_ = 15, P_ = 225, S_ = 8;
constexpr int CHW = C_ * P_;                 // 57600
constexpr size_t NX = (size_t)B_ * CHW;      // 14,745,600

typedef __attribute__((ext_vector_type(4))) short short4v;
typedef __attribute__((ext_vector_type(8))) short short8v;
typedef __attribute__((ext_vector_type(16))) float float16v;

// ---------------- threefry2x32 (verified rounds 2-3) ------------------------
__host__ __device__ inline void tf2x32(uint32_t k0, uint32_t k1,
                                       uint32_t x0, uint32_t x1,
                                       uint32_t& o0, uint32_t& o1) {
  uint32_t ks[3] = {k0, k1, k0 ^ k1 ^ 0x1BD11BDAu};
  const uint32_t rot0[4] = {13u, 15u, 26u, 6u};
  const uint32_t rot1[4] = {17u, 29u, 16u, 24u};
  x0 += ks[0]; x1 += ks[1];
#pragma unroll
  for (int r = 0; r < 5; ++r) {
    const uint32_t* rr = (r & 1) ? rot1 : rot0;
#pragma unroll
    for (int j = 0; j < 4; ++j) {
      x0 += x1;
      x1 = (x1 << rr[j]) | (x1 >> (32 - rr[j]));
      x1 ^= x0;
    }
    x0 += ks[(r + 1) % 3];
    x1 += ks[(r + 2) % 3] + (uint32_t)(r + 1);
  }
  o0 = x0; o1 = x1;
}

__device__ inline float tf_uniform(uint32_t bits) {
  return __uint_as_float((bits >> 9) | 0x3F800000u) - 1.0f;
}

__device__ inline float elu1(float v) { return v > 0.f ? v : expm1f(v); }

__device__ inline unsigned short f2bf(float f) {  // RNE float->bf16
  uint32_t u = __float_as_uint(f);
  return (unsigned short)((u + 0x7FFFu + ((u >> 16) & 1u)) >> 16);
}
__device__ inline float bf2f(unsigned short h) {
  return __uint_as_float(((uint32_t)h) << 16);
}

// LDS rows: stride 36 shorts (18 dwords, gcd(18,32)=2 -> 2-way, free).
__device__ inline short8v ld8(const unsigned short* p) {
  short4v a = *(const short4v*)p;
  short4v b = *(const short4v*)(p + 4);
  return __builtin_shufflevector(a, b, 0, 1, 2, 3, 4, 5, 6, 7);
}
__device__ inline void st8(unsigned short* p, short8v v) {
  *(short4v*)p = __builtin_shufflevector(v, v, 0, 1, 2, 3);
  *(short4v*)(p + 4) = __builtin_shufflevector(v, v, 4, 5, 6, 7);
}

// ---------------- MFMA implicit-GEMM conv (32x32x16, 4 waves) ---------------
// Grid (B, 2): block (b, nh) computes 225 pixels x 128 output channels.
// 4 waves, per-wave tile M=2 x N=4 (acc[2][4] = 128 AGPR): LDS-bytes/MFMA
// = 0.75 vs round-1's 1.0, and halves conflict-prone A-reads per MFMA.
// lsB double-buffered -> ONE barrier per d-step; next weight tile's global
// load issues before the MFMA cluster (latency hidden under compute).
// 2 blocks/CU (256 thr, <=256 regs at launch_bounds(256,2); ~50KB LDS x2).
template <int KS, int DIL, int OFF>
__global__ void __launch_bounds__(256, 2) conv_mfma(
    const unsigned short* __restrict__ xbf, const unsigned short* __restrict__ wt,
    const float* __restrict__ bias, unsigned short* __restrict__ dxg) {
  constexpr int KS2 = KS * KS, WP = W_ + 2 * OFF, PP = WP * (H_ + 2 * OFF);
  __shared__ unsigned short lsA[PP * 36];
  __shared__ unsigned short lsB[2][128 * 36];
  const int b = blockIdx.x, nh = blockIdx.y;
  const int t = threadIdx.x, wv = t >> 6, l = t & 63;
  const int m32 = l & 31, kh8 = l >> 5;
  for (int i = t; i < PP * 36; i += 256) lsA[i] = 0;  // zero borders once
  int rbase[2];
#pragma unroll
  for (int mt = 0; mt < 2; ++mt) {
    int m = (wv * 2 + mt) * 32 + m32;
    int pc = m < P_ ? m : P_ - 1;
    int ph = pc / 15, pw = pc - 15 * ph;
    // Window base in padded coords is (ph, pw): read = ph*WP + pw + DIL*(kh*WP+kw).
    rbase[mt] = ph * WP + pw;
  }
  float16v acc[2][4];
#pragma unroll
  for (int mt = 0; mt < 2; ++mt)
#pragma unroll
    for (int nt = 0; nt < 4; ++nt)
#pragma unroll
      for (int r = 0; r < 16; ++r) acc[mt][nt][r] = 0.f;
  const unsigned short* xb = xbf + (size_t)b * P_ * 256;
  // B-stage: 512 items (128 rows x 4 chunks) over 256 threads = 2 each.
  const int bg = (t >> 2) * 32 + (t & 3) * 8;  // global offset in 8192-elem tile
  const int bl = (t >> 2) * 36 + (t & 3) * 8;  // LDS offset
  const unsigned short* wbase = wt + nh * 4096;
  for (int cb = 0; cb < 8; ++cb) {
    const unsigned short* wcb = wbase + (size_t)(cb * KS2) * 8192;
    // stage A(cb) + B(d=0)->buf0; prior readers done at last d's barrier.
    for (int i = t; i < 900; i += 256) {
      int p = i >> 2, c8 = (i & 3) * 8;
      short8v v = *(const short8v*)(xb + p * 256 + cb * 32 + c8);
      int ph = p / 15, pw = p - 15 * ph;
      st8(&lsA[((ph + OFF) * WP + pw + OFF) * 36 + c8], v);
    }
    {
      short8v v0 = *(const short8v*)(wcb + bg);
      short8v v1 = *(const short8v*)(wcb + bg + 2048);
      st8(&lsB[0][bl], v0);
      st8(&lsB[0][bl + 2304], v1);
    }
    __syncthreads();
    for (int d = 0; d < KS2; ++d) {
      short8v nb0, nb1;
      const bool pre = (d + 1 < KS2);
      if (pre) {  // issue next weight tile's loads before compute
        nb0 = *(const short8v*)(wcb + (size_t)(d + 1) * 8192 + bg);
        nb1 = *(const short8v*)(wcb + (size_t)(d + 1) * 8192 + bg + 2048);
      }
      const unsigned short* bb = lsB[d & 1];
      const int kh = d / KS, kw = d - KS * kh;
      const int doff = DIL * (kh * WP + kw);
#pragma unroll
      for (int k16 = 0; k16 < 2; ++k16) {
        const int ko = k16 * 16 + kh8 * 8;
        short8v af[2], bfr[4];
#pragma unroll
        for (int mt = 0; mt < 2; ++mt)
          af[mt] = ld8(&lsA[(rbase[mt] + doff) * 36 + ko]);
#pragma unroll
        for (int nt = 0; nt < 4; ++nt)
          bfr[nt] = ld8(&bb[(nt * 32 + m32) * 36 + ko]);
#pragma unroll
        for (int mt = 0; mt < 2; ++mt)
#pragma unroll
          for (int nt = 0; nt < 4; ++nt)
            acc[mt][nt] = __builtin_amdgcn_mfma_f32_32x32x16_bf16(
                af[mt], bfr[nt], acc[mt][nt], 0, 0, 0);
      }
      if (pre) {  // write-late into the other buffer (readers drained at d-1)
        unsigned short* bw = lsB[(d + 1) & 1];
        st8(&bw[bl], nb0);
        st8(&bw[bl + 2304], nb1);
      }
      __syncthreads();
    }
  }
#pragma unroll
  for (int nt = 0; nt < 4; ++nt) {
    int o = nh * 128 + nt * 32 + m32;
    float bv = bias[o];
#pragma unroll
    for (int mt = 0; mt < 2; ++mt) {
#pragma unroll
      for (int r = 0; r < 16; ++r) {
        int pixel = (wv * 2 + mt) * 32 + 8 * (r >> 2) + (r & 3) + 4 * kh8;
        if (pixel < P_)
          dxg[((size_t)(b * P_ + pixel)) * 256 + o] = f2bf(elu1(acc[mt][nt][r] + bv));
      }
    }
  }
}

// ---------------- K-blocked GEMM on [B][P][C] (fusion + scan 1x1) -----------
// modes: 0 = write xc; 1 = xc += v; 2 = elu(xc+v+bias) -> xc & xcbf;
//        3 = v+bias -> ybf, block-local LN partial sums -> stats[nh*512+..].
// Same 4-wave M2xN4 structure; BOTH A and B double-buffered -> 1 barrier/kb.
__global__ void __launch_bounds__(256, 2) gemm_kc(
    const unsigned short* __restrict__ A, int rs, int nkb,
    const unsigned short* __restrict__ Bw, const float* __restrict__ bias,
    float* __restrict__ xc, unsigned short* __restrict__ xcbf,
    unsigned short* __restrict__ ybf, float* __restrict__ stats, int mode) {
  __shared__ unsigned short lsA[2][P_ * 36];
  __shared__ unsigned short lsB[2][128 * 36];
  __shared__ float red[8];
  const int b = blockIdx.x, nh = blockIdx.y;
  const int t = threadIdx.x, wv = t >> 6, l = t & 63;
  const int m32 = l & 31, kh8 = l >> 5;
  int prow[2];
#pragma unroll
  for (int mt = 0; mt < 2; ++mt) {
    int m = (wv * 2 + mt) * 32 + m32;
    prow[mt] = m < P_ ? m : P_ - 1;
  }
  float16v acc[2][4];
#pragma unroll
  for (int mt = 0; mt < 2; ++mt)
#pragma unroll
    for (int nt = 0; nt < 4; ++nt)
#pragma unroll
      for (int r = 0; r < 16; ++r) acc[mt][nt][r] = 0.f;
  const unsigned short* Ab = A + (size_t)b * P_ * rs;
  const unsigned short* Bb = Bw + nh * 4096;
  // A-stage: 900 items over 256 threads; static 4-slot unroll (slot3 if t<132).
  const int ap = t >> 2, ac8 = (t & 3) * 8;
  const int al = ap * 36 + ac8;
  const bool hasA3 = t < 132;
  const int bg = (t >> 2) * 32 + (t & 3) * 8, bl = (t >> 2) * 36 + (t & 3) * 8;
  {  // prologue: stage kb=0 into buf0
    const unsigned short* As = Ab + ac8;
    st8(&lsA[0][al], *(const short8v*)(As + (size_t)ap * rs));
    st8(&lsA[0][al + 2304], *(const short8v*)(As + (size_t)(ap + 64) * rs));
    st8(&lsA[0][al + 4608], *(const short8v*)(As + (size_t)(ap + 128) * rs));
    if (hasA3)
      st8(&lsA[0][al + 6912], *(const short8v*)(As + (size_t)(ap + 192) * rs));
    st8(&lsB[0][bl], *(const short8v*)(Bb + bg));
    st8(&lsB[0][bl + 2304], *(const short8v*)(Bb + bg + 2048));
  }
  __syncthreads();
  for (int kb = 0; kb < nkb; ++kb) {
    const bool pre = kb + 1 < nkb;
    short8v na0, na1, na2, na3, nb0, nb1;
    if (pre) {  // issue-early
      const unsigned short* As = Ab + (size_t)(kb + 1) * 32 + ac8;
      na0 = *(const short8v*)(As + (size_t)ap * rs);
      na1 = *(const short8v*)(As + (size_t)(ap + 64) * rs);
      na2 = *(const short8v*)(As + (size_t)(ap + 128) * rs);
      if (hasA3) na3 = *(const short8v*)(As + (size_t)(ap + 192) * rs);
      nb0 = *(const short8v*)(Bb + (size_t)(kb + 1) * 8192 + bg);
      nb1 = *(const short8v*)(Bb + (size_t)(kb + 1) * 8192 + bg + 2048);
    }
    const unsigned short* aa = lsA[kb & 1];
    const unsigned short* bb = lsB[kb & 1];
#pragma unroll
    for (int k16 = 0; k16 < 2; ++k16) {
      const int ko = k16 * 16 + kh8 * 8;
      short8v af[2], bfr[4];
#pragma unroll
      for (int mt = 0; mt < 2; ++mt) af[mt] = ld8(&aa[prow[mt] * 36 + ko]);
#pragma unroll
      for (int nt = 0; nt < 4; ++nt)
        bfr[nt] = ld8(&bb[(nt * 32 + m32) * 36 + ko]);
#pragma unroll
      for (int mt = 0; mt < 2; ++mt)
#pragma unroll
        for (int nt = 0; nt < 4; ++nt)
          acc[mt][nt] = __builtin_amdgcn_mfma_f32_32x32x16_bf16(
              af[mt], bfr[nt], acc[mt][nt], 0, 0, 0);
    }
    if (pre) {  // write-late
      unsigned short* aw = lsA[(kb + 1) & 1];
      unsigned short* bw = lsB[(kb + 1) & 1];
      st8(&aw[al], na0);
      st8(&aw[al + 2304], na1);
      st8(&aw[al + 4608], na2);
      if (hasA3) st8(&aw[al + 6912], na3);
      st8(&bw[bl], nb0);
      st8(&bw[bl + 2304], nb1);
    }
    __syncthreads();
  }
  float s1 = 0.f, s2 = 0.f;
#pragma unroll
  for (int nt = 0; nt < 4; ++nt) {
    int o = nh * 128 + nt * 32 + m32;
    float bv = bias ? bias[o] : 0.f;
#pragma unroll
    for (int mt = 0; mt < 2; ++mt) {
#pragma unroll
      for (int r = 0; r < 16; ++r) {
        int pixel = (wv * 2 + mt) * 32 + 8 * (r >> 2) + (r & 3) + 4 * kh8;
        if (pixel >= P_) continue;
        size_t idx = ((size_t)(b * P_ + pixel)) * 256 + o;
        float v = acc[mt][nt][r];
        if (mode == 0) {
          xc[idx] = v;
        } else if (mode == 1) {
          xc[idx] += v;
        } else if (mode == 2) {
          float e = elu1(xc[idx] + v + bv);
          xc[idx] = e;
          xcbf[idx] = f2bf(e);
        } else {
          v += bv;
          ybf[idx] = f2bf(v);
          s1 += v;
          s2 = fmaf(v, v, s2);
        }
      }
    }
  }
  if (mode == 3) {
#pragma unroll
    for (int off = 32; off; off >>= 1) {
      s1 += __shfl_down(s1, off, 64);
      s2 += __shfl_down(s2, off, 64);
    }
    if (l == 0) { red[wv] = s1; red[4 + wv] = s2; }
    __syncthreads();
    if (t == 0) {
      float a = 0.f, c2 = 0.f;
#pragma unroll
      for (int w = 0; w < 4; ++w) { a += red[w]; c2 += red[4 + w]; }
      stats[nh * 512 + b] = a;
      stats[nh * 512 + 256 + b] = c2;
    }
  }
}

// ---------------- fused LN-apply + ELU + var + threefry update --------------
__global__ void __launch_bounds__(512) step_fused(
    const unsigned short* __restrict__ ybf, float* __restrict__ xc,
    unsigned short* __restrict__ xcbf, const float* __restrict__ stats,
    const float* __restrict__ lnwT, const float* __restrict__ lnbT,
    const float* __restrict__ sp_a, const float* __restrict__ ss_a,
    const float* __restrict__ rw_a, const float* __restrict__ prob_a,
    int s, uint32_t k0, uint32_t k1, int last, float* __restrict__ vout) {
  __shared__ float red[16];
  const int b = blockIdx.x, t = threadIdx.x;
  // stats are 2 partial sums per batch (one per N-half block of gemm_kc).
  const float mean = (stats[b] + stats[512 + b]) * (1.0f / 57600.0f);
  const float var =
      (stats[256 + b] + stats[768 + b]) * (1.0f / 57600.0f) - mean * mean;
  const float rstd = rsqrtf(var + 1e-5f);
  const float sp = sp_a[s], pss = prob_a[s] * ss_a[s], rw1 = 1.0f + rw_a[s];
  float s1 = 0.f, s2 = 0.f;
  const size_t base = (size_t)b * CHW;
  for (int i = t; i < CHW; i += 512) {
    int p = i >> 8, c = i & 255;
    size_t idx = base + i;  // == (b*225+p)*256 + c
    float y = bf2f(ybf[idx]);
    float dx = elu1(fmaf((y - mean) * rstd, lnwT[i], lnbT[i]));
    s1 += dx;
    s2 = fmaf(dx, dx, s2);
    uint32_t j = (uint32_t)b * 57600u + (uint32_t)(c * 225 + p);  // BCHW flat
    uint32_t y0, y1;
    tf2x32(k0, k1, 0u, j, y0, y1);
    float n = tf_uniform(y0 ^ y1);
    float xn = fmaf(xc[idx], rw1, fmaf(dx, sp, n * pss));
    xc[idx] = xn;
    if (!last) xcbf[idx] = f2bf(xn);
  }
  int wv = t >> 6, l = t & 63;
#pragma unroll
  for (int off = 32; off; off >>= 1) {
    s1 += __shfl_down(s1, off, 64);
    s2 += __shfl_down(s2, off, 64);
  }
  if (l == 0) { red[wv] = s1; red[8 + wv] = s2; }
  __syncthreads();
  if (t == 0) {
    float a = 0.f, c2 = 0.f;
#pragma unroll
    for (int w = 0; w < 8; ++w) { a += red[w]; c2 += red[8 + w]; }
    float mv = a * (1.0f / 57600.0f);
    vout[b * 8 + s] = (c2 - 57600.0f * mv * mv) * (1.0f / 57599.0f);
  }
}

// ---------------- prep + epilogue kernels -----------------------------------
__global__ void __launch_bounds__(256) prep_x(const float* __restrict__ x,
                                              unsigned short* __restrict__ xbf) {
  __shared__ unsigned short ts[64 * 232];
  const int b = blockIdx.x, c0 = blockIdx.y * 64;
  const float* xs = x + ((size_t)b * 256 + c0) * P_;
  for (int i = threadIdx.x; i < 64 * P_; i += 256) {
    int c = i / P_, p = i - P_ * c;
    ts[c * 232 + p] = f2bf(xs[c * P_ + p]);
  }
  __syncthreads();
  for (int i = threadIdx.x; i < 64 * P_; i += 256) {
    int p = i >> 6, c = i & 63;
    xbf[((size_t)b * P_ + p) * 256 + c0 + c] = ts[c * 232 + p];
  }
}

__global__ void wt_prep(const float* __restrict__ w, unsigned short* __restrict__ wt,
                        int ks2) {
  int i = blockIdx.x * 256 + threadIdx.x;
  if (i >= 65536 * ks2) return;
  int cl = i & 31, o = (i >> 5) & 255, cbd = i >> 13;
  int d = cbd % ks2, cb = cbd / ks2;
  wt[i] = f2bf(w[((size_t)(o * 256) + cb * 32 + cl) * ks2 + d]);
}

__global__ void wk_prep(const float* __restrict__ w, unsigned short* __restrict__ wt,
                        int K) {
  int i = blockIdx.x * 256 + threadIdx.x;
  if (i >= K * 256) return;
  int kc = i & 31, o = (i >> 5) & 255, kb = i >> 13;
  wt[i] = f2bf(w[(size_t)o * K + kb * 32 + kc]);
}

__global__ void ln_tr(const float* __restrict__ lw, const float* __restrict__ lb,
                      float* __restrict__ ow, float* __restrict__ ob) {
  int p = blockIdx.x, c = threadIdx.x;
  ow[p * 256 + c] = lw[c * P_ + p];
  ob[p * 256 + c] = lb[c * P_ + p];
}

__global__ void __launch_bounds__(256) final_tr(const float* __restrict__ xc,
                                                float* __restrict__ out) {
  __shared__ float ts[64][226];
  const int b = blockIdx.x, c0 = blockIdx.y * 64;
  for (int i = threadIdx.x; i < 64 * P_; i += 256) {
    int cl = i & 63, p = i >> 6;
    ts[cl][p] = xc[((size_t)(b * P_ + p)) * 256 + c0 + cl];
  }
  __syncthreads();
  for (int i = threadIdx.x; i < 64 * P_; i += 256) {
    int cl = i / P_, p = i - P_ * cl;
    out[((size_t)(b * 256 + c0 + cl)) * P_ + p] = ts[cl][p];
  }
}

// ---------------- launch ----------------------------------------------------
extern "C" void kernel_launch(void* const* d_in, const int* in_sizes, int n_in,
                              void* d_out, int out_size, void* d_ws,
                              size_t ws_size, hipStream_t stream) {
  const float* x = (const float*)d_in[0];
  const float* prob = (const float*)d_in[1];
  const float* w3 = (const float*)d_in[2];
  const float* b3 = (const float*)d_in[3];
  const float* w3d = (const float*)d_in[4];
  const float* b3d = (const float*)d_in[5];
  const float* w5 = (const float*)d_in[6];
  const float* b5 = (const float*)d_in[7];
  const float* w7 = (const float*)d_in[8];
  const float* b7 = (const float*)d_in[9];
  const float* wf = (const float*)d_in[10];
  const float* bfus = (const float*)d_in[11];
  const float* w1 = (const float*)d_in[12];
  const float* b1 = (const float*)d_in[13];
  const float* lnw = (const float*)d_in[14];
  const float* lnb = (const float*)d_in[15];
  const float* sp = (const float*)d_in[16];
  const float* ss = (const float*)d_in[17];
  const float* rw = (const float*)d_in[18];
  float* out = (float*)d_out;

  // ws layout (117,964,800 B, proven budget):
  unsigned short* xbf = (unsigned short*)d_ws;                      // 29,491,200
  float* xc = (float*)((char*)d_ws + 29491200);                     // 58,982,400
  unsigned short* dxg = (unsigned short*)((char*)d_ws + 88473600);  // 29,491,200
  unsigned short* xcbf = xbf;  // reuse: xbf dead after conv7
  unsigned short* ybf = dxg;   // reuse: dxg dead after fusion

  // d_out[0..NX*4) is scratch until final_tr.
  char* sc = (char*)d_out;
  unsigned short* wT3 = (unsigned short*)(sc + 0);
  unsigned short* wT3d = (unsigned short*)(sc + 1179648);
  unsigned short* wT5 = (unsigned short*)(sc + 2359296);
  unsigned short* wT7 = (unsigned short*)(sc + 5636096);
  unsigned short* wfT = (unsigned short*)(sc + 12058624);
  unsigned short* w1T = (unsigned short*)(sc + 12582912);
  float* lnwT = (float*)(sc + 12713984);
  float* lnbT = (float*)(sc + 12944384);
  float* stats = (float*)(sc + 13174784);  // [2 halves][2 sums][256] raw sums

  prep_x<<<dim3(B_, 4), 256, 0, stream>>>(x, xbf);
  wt_prep<<<(65536 * 9 + 255) / 256, 256, 0, stream>>>(w3, wT3, 9);
  wt_prep<<<(65536 * 9 + 255) / 256, 256, 0, stream>>>(w3d, wT3d, 9);
  wt_prep<<<(65536 * 25 + 255) / 256, 256, 0, stream>>>(w5, wT5, 25);
  wt_prep<<<(65536 * 49 + 255) / 256, 256, 0, stream>>>(w7, wT7, 49);
  wk_prep<<<1024, 256, 0, stream>>>(wf, wfT, 1024);
  wk_prep<<<256, 256, 0, stream>>>(w1, w1T, 256);
  ln_tr<<<P_, 256, 0, stream>>>(lnw, lnb, lnwT, lnbT);

  conv_mfma<3, 1, 1><<<dim3(B_, 2), 256, 0, stream>>>(xbf, wT3, b3, dxg);
  gemm_kc<<<dim3(B_, 2), 256, 0, stream>>>(dxg, 256, 8, wfT, nullptr, xc, nullptr, nullptr, nullptr, 0);
  conv_mfma<3, 2, 2><<<dim3(B_, 2), 256, 0, stream>>>(xbf, wT3d, b3d, dxg);
  gemm_kc<<<dim3(B_, 2), 256, 0, stream>>>(dxg, 256, 8, wfT + 65536, nullptr, xc, nullptr, nullptr, nullptr, 1);
  conv_mfma<5, 1, 2><<<dim3(B_, 2), 256, 0, stream>>>(xbf, wT5, b5, dxg);
  gemm_kc<<<dim3(B_, 2), 256, 0, stream>>>(dxg, 256, 8, wfT + 131072, nullptr, xc, nullptr, nullptr, nullptr, 1);
  conv_mfma<7, 1, 3><<<dim3(B_, 2), 256, 0, stream>>>(xbf, wT7, b7, dxg);
  gemm_kc<<<dim3(B_, 2), 256, 0, stream>>>(dxg, 256, 8, wfT + 196608, bfus, xc, xcbf, nullptr, nullptr, 2);

  gemm_kc<<<dim3(B_, 2), 256, 0, stream>>>(xcbf, 256, 8, w1T, b1, nullptr, nullptr, ybf, stats, 3);
  for (int si = 0; si < S_; ++si) {
    uint32_t k0s, k1s;
    tf2x32(0u, 42u, 0u, (uint32_t)si, k0s, k1s);  // fold_in(key(42), si)
    step_fused<<<B_, 512, 0, stream>>>(ybf, xc, xcbf, stats, lnwT, lnbT, sp, ss, rw,
                                       prob, si, k0s, k1s, si == S_ - 1, out + NX);
    if (si < S_ - 1)
      gemm_kc<<<dim3(B_, 2), 256, 0, stream>>>(xcbf, 256, 8, w1T, b1, nullptr, nullptr, ybf, stats, 3);
  }

  final_tr<<<dim3(B_, 4), 256, 0, stream>>>(xc, out);
}

// Round 3
// 1703.319 us; speedup vs baseline: 1.3174x; 1.3174x over previous
//
#include <hip/hip_runtime.h>
#include <cstdint>

// B=256, C=256, H=W=15, S=8.
constexpr int B_ = 256, C_ = 256, H_ = 15, W_ = 15, P_ = 225, S_ = 8;
constexpr int CHW = C_ * P_;                 // 57600
constexpr size_t NX = (size_t)B_ * CHW;      // 14,745,600

typedef __attribute__((ext_vector_type(8))) short short8v;
typedef __attribute__((ext_vector_type(4))) float float4v;
typedef __attribute__((ext_vector_type(16))) float float16v;

// ---------------- threefry2x32 (verified rounds 2-3) ------------------------
__host__ __device__ inline void tf2x32(uint32_t k0, uint32_t k1,
                                       uint32_t x0, uint32_t x1,
                                       uint32_t& o0, uint32_t& o1) {
  uint32_t ks[3] = {k0, k1, k0 ^ k1 ^ 0x1BD11BDAu};
  const uint32_t rot0[4] = {13u, 15u, 26u, 6u};
  const uint32_t rot1[4] = {17u, 29u, 16u, 24u};
  x0 += ks[0]; x1 += ks[1];
#pragma unroll
  for (int r = 0; r < 5; ++r) {
    const uint32_t* rr = (r & 1) ? rot1 : rot0;
#pragma unroll
    for (int j = 0; j < 4; ++j) {
      x0 += x1;
      x1 = (x1 << rr[j]) | (x1 >> (32 - rr[j]));
      x1 ^= x0;
    }
    x0 += ks[(r + 1) % 3];
    x1 += ks[(r + 2) % 3] + (uint32_t)(r + 1);
  }
  o0 = x0; o1 = x1;
}

__device__ inline float tf_uniform(uint32_t bits) {
  return __uint_as_float((bits >> 9) | 0x3F800000u) - 1.0f;
}

__device__ inline float elu1(float v) { return v > 0.f ? v : expm1f(v); }

__device__ inline unsigned short f2bf(float f) {  // RNE float->bf16
  uint32_t u = __float_as_uint(f);
  return (unsigned short)((u + 0x7FFFu + ((u >> 16) & 1u)) >> 16);
}
__device__ inline float bf2f(unsigned short h) {
  return __uint_as_float(((uint32_t)h) << 16);
}

// ---------------- MFMA implicit-GEMM conv (32x32x16, 4 waves) ---------------
// k-major LDS layout [k8-plane][row][8 shorts]: every fragment access is one
// aligned ds_read/write_b128 with contiguous lane addresses -> conflict-free,
// half the LDS instruction count of the old stride-36 b64-pair layout.
// Grid (B,2): block (b,nh) = 225 pixels x 128 out-channels. 4 waves, M2xN4
// (acc[2][4]); lsB double-buffered, 1 barrier/d-step, B prefetched via regs.
template <int KS, int DIL, int OFF>
__global__ void __launch_bounds__(256, 2) conv_mfma(
    const unsigned short* __restrict__ xbf, const unsigned short* __restrict__ wt,
    const float* __restrict__ bias, unsigned short* __restrict__ dxg) {
  constexpr int KS2 = KS * KS, WP = W_ + 2 * OFF, PP = WP * (H_ + 2 * OFF);
  __shared__ __align__(16) unsigned short lsA[4 * PP * 8];      // [pl][pix][8]
  __shared__ __align__(16) unsigned short lsB[2][4 * 128 * 8];  // [buf][pl][row][8]
  const int b = blockIdx.x, nh = blockIdx.y;
  const int t = threadIdx.x, wv = t >> 6, l = t & 63;
  const int m32 = l & 31, kh8 = l >> 5;
  for (int i = t; i < 4 * PP * 8; i += 256) lsA[i] = 0;  // zero borders once
  int rbase[2];
#pragma unroll
  for (int mt = 0; mt < 2; ++mt) {
    int m = (wv * 2 + mt) * 32 + m32;
    int pc = m < P_ ? m : P_ - 1;
    int ph = pc / 15, pw = pc - 15 * ph;
    rbase[mt] = ph * WP + pw;  // padded-coord window base
  }
  float16v acc[2][4];
#pragma unroll
  for (int mt = 0; mt < 2; ++mt)
#pragma unroll
    for (int nt = 0; nt < 4; ++nt)
#pragma unroll
      for (int r = 0; r < 16; ++r) acc[mt][nt][r] = 0.f;
  const unsigned short* xb = xbf + (size_t)b * P_ * 256;
  // B-stage: thread t handles rows (t>>2) and (t>>2)+64, k-plane t&3.
  const int bl = ((t & 3) * 128 + (t >> 2)) * 8;
  const unsigned short* wbase = wt + nh * 4096;
  for (int cb = 0; cb < 8; ++cb) {
    const unsigned short* wcb = wbase + (size_t)(cb * KS2) * 8192;
    for (int i = t; i < 900; i += 256) {
      int p = i >> 2, pl = i & 3;
      short8v v = *(const short8v*)(xb + p * 256 + cb * 32 + pl * 8);
      int ph = p / 15, pw = p - 15 * ph;
      *(short8v*)&lsA[(pl * PP + (ph + OFF) * WP + pw + OFF) * 8] = v;
    }
    {
      short8v v0 = *(const short8v*)(wcb + t * 8);
      short8v v1 = *(const short8v*)(wcb + 2048 + t * 8);
      *(short8v*)&lsB[0][bl] = v0;
      *(short8v*)&lsB[0][bl + 512] = v1;
    }
    __syncthreads();
    for (int d = 0; d < KS2; ++d) {
      short8v nb0, nb1;
      const bool pre = (d + 1 < KS2);
      if (pre) {  // issue next weight tile's loads before compute
        nb0 = *(const short8v*)(wcb + (size_t)(d + 1) * 8192 + t * 8);
        nb1 = *(const short8v*)(wcb + (size_t)(d + 1) * 8192 + 2048 + t * 8);
      }
      const unsigned short* bb = lsB[d & 1];
      const int kh = d / KS, kw = d - KS * kh;
      const int doff = DIL * (kh * WP + kw);
#pragma unroll
      for (int k16 = 0; k16 < 2; ++k16) {
        const int pl = k16 * 2 + kh8;
        short8v af[2], bfr[4];
#pragma unroll
        for (int mt = 0; mt < 2; ++mt)
          af[mt] = *(const short8v*)&lsA[(pl * PP + rbase[mt] + doff) * 8];
#pragma unroll
        for (int nt = 0; nt < 4; ++nt)
          bfr[nt] = *(const short8v*)&bb[(pl * 128 + nt * 32 + m32) * 8];
#pragma unroll
        for (int mt = 0; mt < 2; ++mt)
#pragma unroll
          for (int nt = 0; nt < 4; ++nt)
            acc[mt][nt] = __builtin_amdgcn_mfma_f32_32x32x16_bf16(
                af[mt], bfr[nt], acc[mt][nt], 0, 0, 0);
      }
      if (pre) {  // write-late into the other buffer
        unsigned short* bw = lsB[(d + 1) & 1];
        *(short8v*)&bw[bl] = nb0;
        *(short8v*)&bw[bl + 512] = nb1;
      }
      __syncthreads();
    }
  }
#pragma unroll
  for (int nt = 0; nt < 4; ++nt) {
    int o = nh * 128 + nt * 32 + m32;
    float bv = bias[o];
#pragma unroll
    for (int mt = 0; mt < 2; ++mt) {
#pragma unroll
      for (int r = 0; r < 16; ++r) {
        int pixel = (wv * 2 + mt) * 32 + 8 * (r >> 2) + (r & 3) + 4 * kh8;
        if (pixel < P_)
          dxg[((size_t)(b * P_ + pixel)) * 256 + o] = f2bf(elu1(acc[mt][nt][r] + bv));
      }
    }
  }
}

// ---------------- K-blocked GEMM on [B][P][256] (fusion + scan 1x1) ---------
// A source: bf16 A0 (kb<8) / A1 (kb>=8), or f32 Af (converted during staging).
// modes: 0 = xc = v; 2 = xc = elu(xc+v+bias); 3 = ybf = f2bf(v+bias) + LN sums.
// 8 waves / 512 threads (memory phases need the waves); k-major LDS.
__global__ void __launch_bounds__(512, 4) gemm_kc(
    const unsigned short* __restrict__ A0, const unsigned short* __restrict__ A1,
    const float* __restrict__ Af, int nkb,
    const unsigned short* __restrict__ Bw, const float* __restrict__ bias,
    float* __restrict__ xc, unsigned short* __restrict__ ybf,
    float* __restrict__ stats, int mode) {
  __shared__ __align__(16) unsigned short lsA[4 * P_ * 8];   // [pl][p][8]
  __shared__ __align__(16) unsigned short lsB[4 * 128 * 8];  // [pl][row][8]
  __shared__ float red[16];
  const int b = blockIdx.x, nh = blockIdx.y;
  const int t = threadIdx.x, wv = t >> 6, l = t & 63;
  const int m32 = l & 31, kh8 = l >> 5;
  const int mp = wv & 3, nq = wv >> 2;
  int prow[2];
#pragma unroll
  for (int mt = 0; mt < 2; ++mt) {
    int m = (mp * 2 + mt) * 32 + m32;
    prow[mt] = m < P_ ? m : P_ - 1;
  }
  float16v acc[2][2];
#pragma unroll
  for (int mt = 0; mt < 2; ++mt)
#pragma unroll
    for (int nt = 0; nt < 2; ++nt)
#pragma unroll
      for (int r = 0; r < 16; ++r) acc[mt][nt][r] = 0.f;
  const float* Afb = Af ? Af + (size_t)b * P_ * 256 : nullptr;
  for (int kb = 0; kb < nkb; ++kb) {
    __syncthreads();
    if (Af) {
      for (int i = t; i < 900; i += 512) {
        int p = i >> 2, pl = i & 3;
        const float* src = Afb + (size_t)p * 256 + kb * 32 + pl * 8;
        float4v f0 = *(const float4v*)src;
        float4v f1 = *(const float4v*)(src + 4);
        short8v v;
        v[0] = (short)f2bf(f0[0]); v[1] = (short)f2bf(f0[1]);
        v[2] = (short)f2bf(f0[2]); v[3] = (short)f2bf(f0[3]);
        v[4] = (short)f2bf(f1[0]); v[5] = (short)f2bf(f1[1]);
        v[6] = (short)f2bf(f1[2]); v[7] = (short)f2bf(f1[3]);
        *(short8v*)&lsA[(pl * P_ + p) * 8] = v;
      }
    } else {
      const unsigned short* Asb =
          ((kb & 8) ? A1 : A0) + (size_t)b * P_ * 256;
      for (int i = t; i < 900; i += 512) {
        int p = i >> 2, pl = i & 3;
        short8v v = *(const short8v*)(Asb + (size_t)p * 256 + (kb & 7) * 32 + pl * 8);
        *(short8v*)&lsA[(pl * P_ + p) * 8] = v;
      }
    }
    {
      short8v v = *(const short8v*)(Bw + (size_t)kb * 8192 + nh * 4096 + t * 8);
      *(short8v*)&lsB[((t & 3) * 128 + (t >> 2)) * 8] = v;
    }
    __syncthreads();
#pragma unroll
    for (int k16 = 0; k16 < 2; ++k16) {
      const int pl = k16 * 2 + kh8;
      short8v af[2], bfr[2];
#pragma unroll
      for (int mt = 0; mt < 2; ++mt)
        af[mt] = *(const short8v*)&lsA[(pl * P_ + prow[mt]) * 8];
#pragma unroll
      for (int nt = 0; nt < 2; ++nt)
        bfr[nt] = *(const short8v*)&lsB[(pl * 128 + (nq * 2 + nt) * 32 + m32) * 8];
#pragma unroll
      for (int mt = 0; mt < 2; ++mt)
#pragma unroll
        for (int nt = 0; nt < 2; ++nt)
          acc[mt][nt] = __builtin_amdgcn_mfma_f32_32x32x16_bf16(
              af[mt], bfr[nt], acc[mt][nt], 0, 0, 0);
    }
  }
  float s1 = 0.f, s2 = 0.f;
#pragma unroll
  for (int nt = 0; nt < 2; ++nt) {
    int o = nh * 128 + (nq * 2 + nt) * 32 + m32;
    float bv = bias ? bias[o] : 0.f;
#pragma unroll
    for (int mt = 0; mt < 2; ++mt) {
#pragma unroll
      for (int r = 0; r < 16; ++r) {
        int pixel = (mp * 2 + mt) * 32 + 8 * (r >> 2) + (r & 3) + 4 * kh8;
        if (pixel >= P_) continue;
        size_t idx = ((size_t)(b * P_ + pixel)) * 256 + o;
        float v = acc[mt][nt][r];
        if (mode == 0) {
          xc[idx] = v;
        } else if (mode == 2) {
          xc[idx] = elu1(xc[idx] + v + bv);
        } else {
          v += bv;
          ybf[idx] = f2bf(v);
          s1 += v;
          s2 = fmaf(v, v, s2);
        }
      }
    }
  }
  if (mode == 3) {
#pragma unroll
    for (int off = 32; off; off >>= 1) {
      s1 += __shfl_down(s1, off, 64);
      s2 += __shfl_down(s2, off, 64);
    }
    if (l == 0) { red[wv] = s1; red[8 + wv] = s2; }
    __syncthreads();
    if (t == 0) {
      float a = 0.f, c2 = 0.f;
#pragma unroll
      for (int w = 0; w < 8; ++w) { a += red[w]; c2 += red[8 + w]; }
      stats[nh * 512 + b] = a;
      stats[nh * 512 + 256 + b] = c2;
    }
  }
}

// ---------------- fused LN-apply + ELU + var + threefry update --------------
// Vectorized: 8 consecutive elements per thread per iteration (G13).
__global__ void __launch_bounds__(512) step_fused(
    const unsigned short* __restrict__ ybf, float* __restrict__ xc,
    unsigned short* __restrict__ xcbf, const float* __restrict__ stats,
    const float* __restrict__ lnwT, const float* __restrict__ lnbT,
    const float* __restrict__ sp_a, const float* __restrict__ ss_a,
    const float* __restrict__ rw_a, const float* __restrict__ prob_a,
    int s, uint32_t k0, uint32_t k1, int last, float* __restrict__ vout) {
  __shared__ float red[16];
  const int b = blockIdx.x, t = threadIdx.x;
  const float mean = (stats[b] + stats[512 + b]) * (1.0f / 57600.0f);
  const float var =
      (stats[256 + b] + stats[768 + b]) * (1.0f / 57600.0f) - mean * mean;
  const float rstd = rsqrtf(var + 1e-5f);
  const float sp = sp_a[s], pss = prob_a[s] * ss_a[s], rw1 = 1.0f + rw_a[s];
  float s1 = 0.f, s2 = 0.f;
  const size_t base = (size_t)b * CHW;
  for (int g = t; g < 7200; g += 512) {
    int i0 = g * 8;
    int p = i0 >> 8, c0 = i0 & 255;  // 8-group never crosses a p boundary
    size_t idx = base + i0;
    short8v yv = *(const short8v*)(ybf + idx);
    float4v x0 = *(const float4v*)(xc + idx);
    float4v x1 = *(const float4v*)(xc + idx + 4);
    float4v lw0 = *(const float4v*)(lnwT + i0);
    float4v lw1 = *(const float4v*)(lnwT + i0 + 4);
    float4v lb0 = *(const float4v*)(lnbT + i0);
    float4v lb1 = *(const float4v*)(lnbT + i0 + 4);
    const uint32_t jbase = (uint32_t)b * 57600u + (uint32_t)c0 * 225u + (uint32_t)p;
    float4v o0, o1;
    short8v ob;
#pragma unroll
    for (int e = 0; e < 8; ++e) {
      float y = bf2f((unsigned short)yv[e]);
      float lw = e < 4 ? lw0[e] : lw1[e - 4];
      float lb = e < 4 ? lb0[e] : lb1[e - 4];
      float xo = e < 4 ? x0[e] : x1[e - 4];
      float dx = elu1(fmaf((y - mean) * rstd, lw, lb));
      s1 += dx;
      s2 = fmaf(dx, dx, s2);
      uint32_t y0, y1;
      tf2x32(k0, k1, 0u, jbase + 225u * (uint32_t)e, y0, y1);
      float n = tf_uniform(y0 ^ y1);
      float xn = fmaf(xo, rw1, fmaf(dx, sp, n * pss));
      if (e < 4) o0[e] = xn; else o1[e - 4] = xn;
      ob[e] = (short)f2bf(xn);
    }
    *(float4v*)(xc + idx) = o0;
    *(float4v*)(xc + idx + 4) = o1;
    if (!last) *(short8v*)(xcbf + idx) = ob;
  }
  int wv = t >> 6, l = t & 63;
#pragma unroll
  for (int off = 32; off; off >>= 1) {
    s1 += __shfl_down(s1, off, 64);
    s2 += __shfl_down(s2, off, 64);
  }
  if (l == 0) { red[wv] = s1; red[8 + wv] = s2; }
  __syncthreads();
  if (t == 0) {
    float a = 0.f, c2 = 0.f;
#pragma unroll
    for (int w = 0; w < 8; ++w) { a += red[w]; c2 += red[8 + w]; }
    float mv = a * (1.0f / 57600.0f);
    vout[b * 8 + s] = (c2 - 57600.0f * mv * mv) * (1.0f / 57599.0f);
  }
}

// ---------------- prep + epilogue kernels -----------------------------------
__global__ void __launch_bounds__(256) prep_x(const float* __restrict__ x,
                                              unsigned short* __restrict__ xbf) {
  __shared__ unsigned short ts[64 * 232];
  const int b = blockIdx.x, c0 = blockIdx.y * 64;
  const float* xs = x + ((size_t)b * 256 + c0) * P_;
  for (int i = threadIdx.x; i < 64 * P_; i += 256) {
    int c = i / P_, p = i - P_ * c;
    ts[c * 232 + p] = f2bf(xs[c * P_ + p]);
  }
  __syncthreads();
  for (int i = threadIdx.x; i < 64 * P_; i += 256) {
    int p = i >> 6, c = i & 63;
    xbf[((size_t)b * P_ + p) * 256 + c0 + c] = ts[c * 232 + p];
  }
}

__global__ void wt_prep(const float* __restrict__ w, unsigned short* __restrict__ wt,
                        int ks2) {
  int i = blockIdx.x * 256 + threadIdx.x;
  if (i >= 65536 * ks2) return;
  int cl = i & 31, o = (i >> 5) & 255, cbd = i >> 13;
  int d = cbd % ks2, cb = cbd / ks2;
  wt[i] = f2bf(w[((size_t)(o * 256) + cb * 32 + cl) * ks2 + d]);
}

__global__ void wk_prep(const float* __restrict__ w, unsigned short* __restrict__ wt,
                        int K) {
  int i = blockIdx.x * 256 + threadIdx.x;
  if (i >= K * 256) return;
  int kc = i & 31, o = (i >> 5) & 255, kb = i >> 13;
  wt[i] = f2bf(w[(size_t)o * K + kb * 32 + kc]);
}

__global__ void ln_tr(const float* __restrict__ lw, const float* __restrict__ lb,
                      float* __restrict__ ow, float* __restrict__ ob) {
  int p = blockIdx.x, c = threadIdx.x;
  ow[p * 256 + c] = lw[c * P_ + p];
  ob[p * 256 + c] = lb[c * P_ + p];
}

__global__ void __launch_bounds__(256) final_tr(const float* __restrict__ xc,
                                                float* __restrict__ out) {
  __shared__ float ts[64][226];
  const int b = blockIdx.x, c0 = blockIdx.y * 64;
  for (int i = threadIdx.x; i < 64 * P_; i += 256) {
    int cl = i & 63, p = i >> 6;
    ts[cl][p] = xc[((size_t)(b * P_ + p)) * 256 + c0 + cl];
  }
  __syncthreads();
  for (int i = threadIdx.x; i < 64 * P_; i += 256) {
    int cl = i / P_, p = i - P_ * cl;
    out[((size_t)(b * 256 + c0 + cl)) * P_ + p] = ts[cl][p];
  }
}

// ---------------- launch ----------------------------------------------------
extern "C" void kernel_launch(void* const* d_in, const int* in_sizes, int n_in,
                              void* d_out, int out_size, void* d_ws,
                              size_t ws_size, hipStream_t stream) {
  const float* x = (const float*)d_in[0];
  const float* prob = (const float*)d_in[1];
  const float* w3 = (const float*)d_in[2];
  const float* b3 = (const float*)d_in[3];
  const float* w3d = (const float*)d_in[4];
  const float* b3d = (const float*)d_in[5];
  const float* w5 = (const float*)d_in[6];
  const float* b5 = (const float*)d_in[7];
  const float* w7 = (const float*)d_in[8];
  const float* b7 = (const float*)d_in[9];
  const float* wf = (const float*)d_in[10];
  const float* bfus = (const float*)d_in[11];
  const float* w1 = (const float*)d_in[12];
  const float* b1 = (const float*)d_in[13];
  const float* lnw = (const float*)d_in[14];
  const float* lnb = (const float*)d_in[15];
  const float* sp = (const float*)d_in[16];
  const float* ss = (const float*)d_in[17];
  const float* rw = (const float*)d_in[18];
  float* out = (float*)d_out;

  // ws layout (117,964,800 B):
  //   phase 1 (convs+fusion): dxg0 [0,29.5M) dxg1 [29.5M,59M) xc [59M,118M)
  //   phase 2 (scan):         xcbf [0,29.5M) ybf  [29.5M,59M) xc [59M,118M)
  unsigned short* dxg0 = (unsigned short*)d_ws;
  unsigned short* dxg1 = (unsigned short*)((char*)d_ws + 29491200);
  float* xc = (float*)((char*)d_ws + 58982400);
  unsigned short* xcbf = dxg0;  // reuse after fusion
  unsigned short* ybf = dxg1;   // reuse after fusion

  // d_out[0..59MB) is scratch until final_tr.
  char* sc = (char*)d_out;
  unsigned short* wT3 = (unsigned short*)(sc + 0);
  unsigned short* wT3d = (unsigned short*)(sc + 1179648);
  unsigned short* wT5 = (unsigned short*)(sc + 2359296);
  unsigned short* wT7 = (unsigned short*)(sc + 5636096);
  unsigned short* wfT = (unsigned short*)(sc + 12058624);
  unsigned short* w1T = (unsigned short*)(sc + 12582912);
  float* lnwT = (float*)(sc + 12713984);
  float* lnbT = (float*)(sc + 12944384);
  unsigned short* xbf = (unsigned short*)(sc + 13174784);  // 29.5MB, ends 42.7M
  float* stats = (float*)(sc + 42665984);  // [2 halves][2 sums][256]

  prep_x<<<dim3(B_, 4), 256, 0, stream>>>(x, xbf);
  wt_prep<<<(65536 * 9 + 255) / 256, 256, 0, stream>>>(w3, wT3, 9);
  wt_prep<<<(65536 * 9 + 255) / 256, 256, 0, stream>>>(w3d, wT3d, 9);
  wt_prep<<<(65536 * 25 + 255) / 256, 256, 0, stream>>>(w5, wT5, 25);
  wt_prep<<<(65536 * 49 + 255) / 256, 256, 0, stream>>>(w7, wT7, 49);
  wk_prep<<<1024, 256, 0, stream>>>(wf, wfT, 1024);
  wk_prep<<<256, 256, 0, stream>>>(w1, w1T, 256);
  ln_tr<<<P_, 256, 0, stream>>>(lnw, lnb, lnwT, lnbT);

  // multi-scale perception: pairwise convs + two K=512 fusion GEMMs
  conv_mfma<3, 1, 1><<<dim3(B_, 2), 256, 0, stream>>>(xbf, wT3, b3, dxg0);
  conv_mfma<3, 2, 2><<<dim3(B_, 2), 256, 0, stream>>>(xbf, wT3d, b3d, dxg1);
  gemm_kc<<<dim3(B_, 2), 512, 0, stream>>>(dxg0, dxg1, nullptr, 16, wfT,
                                           nullptr, xc, nullptr, nullptr, 0);
  conv_mfma<5, 1, 2><<<dim3(B_, 2), 256, 0, stream>>>(xbf, wT5, b5, dxg0);
  conv_mfma<7, 1, 3><<<dim3(B_, 2), 256, 0, stream>>>(xbf, wT7, b7, dxg1);
  gemm_kc<<<dim3(B_, 2), 512, 0, stream>>>(dxg0, dxg1, nullptr, 16, wfT + 131072,
                                           bfus, xc, nullptr, nullptr, 2);

  // scan: first 1x1 GEMM stages from f32 xc (converted in staging) to avoid
  // a bf16-copy race; later ones read xcbf written by step_fused.
  gemm_kc<<<dim3(B_, 2), 512, 0, stream>>>(nullptr, nullptr, xc, 8, w1T, b1,
                                           nullptr, ybf, stats, 3);
  for (int si = 0; si < S_; ++si) {
    uint32_t k0s, k1s;
    tf2x32(0u, 42u, 0u, (uint32_t)si, k0s, k1s);  // fold_in(key(42), si)
    step_fused<<<B_, 512, 0, stream>>>(ybf, xc, xcbf, stats, lnwT, lnbT, sp, ss, rw,
                                       prob, si, k0s, k1s, si == S_ - 1, out + NX);
    if (si < S_ - 1)
      gemm_kc<<<dim3(B_, 2), 512, 0, stream>>>(xcbf, xcbf, nullptr, 8, w1T, b1,
                                               nullptr, ybf, stats, 3);
  }

  final_tr<<<dim3(B_, 4), 256, 0, stream>>>(xc, out);
}

// Round 4
// 1688.419 us; speedup vs baseline: 1.3290x; 1.0088x over previous
//
#include <hip/hip_runtime.h>
#include <cstdint>

// B=256, C=256, H=W=15, S=8.
constexpr int B_ = 256, C_ = 256, H_ = 15, W_ = 15, P_ = 225, S_ = 8;
constexpr int CHW = C_ * P_;                 // 57600
constexpr size_t NX = (size_t)B_ * CHW;      // 14,745,600

typedef __attribute__((ext_vector_type(8))) short short8v;
typedef __attribute__((ext_vector_type(4))) float float4v;
typedef __attribute__((ext_vector_type(16))) float float16v;

// ---------------- threefry2x32 (verified rounds 2-3) ------------------------
__host__ __device__ inline void tf2x32(uint32_t k0, uint32_t k1,
                                       uint32_t x0, uint32_t x1,
                                       uint32_t& o0, uint32_t& o1) {
  uint32_t ks[3] = {k0, k1, k0 ^ k1 ^ 0x1BD11BDAu};
  const uint32_t rot0[4] = {13u, 15u, 26u, 6u};
  const uint32_t rot1[4] = {17u, 29u, 16u, 24u};
  x0 += ks[0]; x1 += ks[1];
#pragma unroll
  for (int r = 0; r < 5; ++r) {
    const uint32_t* rr = (r & 1) ? rot1 : rot0;
#pragma unroll
    for (int j = 0; j < 4; ++j) {
      x0 += x1;
      x1 = (x1 << rr[j]) | (x1 >> (32 - rr[j]));
      x1 ^= x0;
    }
    x0 += ks[(r + 1) % 3];
    x1 += ks[(r + 2) % 3] + (uint32_t)(r + 1);
  }
  o0 = x0; o1 = x1;
}

__device__ inline float tf_uniform(uint32_t bits) {
  return __uint_as_float((bits >> 9) | 0x3F800000u) - 1.0f;
}

__device__ inline float elu1(float v) { return v > 0.f ? v : expm1f(v); }

__device__ inline unsigned short f2bf(float f) {  // RNE float->bf16
  uint32_t u = __float_as_uint(f);
  return (unsigned short)((u + 0x7FFFu + ((u >> 16) & 1u)) >> 16);
}
__device__ inline float bf2f(unsigned short h) {
  return __uint_as_float(((uint32_t)h) << 16);
}

// ---------------- MFMA implicit-GEMM conv (32x32x16, 4 waves) ---------------
// k-major LDS layout [plane][row][8 shorts]: every fragment access is one
// aligned b128 with contiguous lane addresses.
// CHUNKED B-STAGING (this round): stage 3 weight d-planes per chunk, double-
// buffered, next chunk's global loads issued BEFORE the 48-MFMA cluster and
// LDS-written after it -> ONE barrier per 3 d-steps (was 2 per d-step).
// Removes the per-d-step barrier convoy that capped MFMA util at ~48%.
// Grid (B,2): block (b,nh) = 225 pixels x 128 out-channels, 4 waves, M2xN4.
// LDS: lsA 4*PP*16B + lsB 2*24KB; conv7 = 76KB -> 2 blocks/CU (152KB).
template <int KS, int DIL, int OFF>
__global__ void __launch_bounds__(256, 2) conv_mfma(
    const unsigned short* __restrict__ xbf, const unsigned short* __restrict__ wt,
    const float* __restrict__ bias, unsigned short* __restrict__ dxg) {
  constexpr int KS2 = KS * KS, WP = W_ + 2 * OFF, PP = WP * (H_ + 2 * OFF);
  constexpr int NCH = (KS2 + 2) / 3;  // chunks of 3 d-planes per k-block
  __shared__ __align__(16) unsigned short lsA[4 * PP * 8];        // [pl][pix][8]
  __shared__ __align__(16) unsigned short lsB[2][3 * 4 * 128 * 8]; // [buf][dd*4+pl][row][8]
  const int b = blockIdx.x, nh = blockIdx.y;
  const int t = threadIdx.x, wv = t >> 6, l = t & 63;
  const int m32 = l & 31, kh8 = l >> 5;
  for (int i = t; i < 4 * PP * 8; i += 256) lsA[i] = 0;  // zero borders once
  int rbase[2];
#pragma unroll
  for (int mt = 0; mt < 2; ++mt) {
    int m = (wv * 2 + mt) * 32 + m32;
    int pc = m < P_ ? m : P_ - 1;
    int ph = pc / 15, pw = pc - 15 * ph;
    rbase[mt] = ph * WP + pw;  // padded-coord window base
  }
  float16v acc[2][4];
#pragma unroll
  for (int mt = 0; mt < 2; ++mt)
#pragma unroll
    for (int nt = 0; nt < 4; ++nt)
#pragma unroll
      for (int r = 0; r < 16; ++r) acc[mt][nt][r] = 0.f;
  const unsigned short* xb = xbf + (size_t)b * P_ * 256;
  const unsigned short* wbase = wt + nh * 4096;
  // ---- prologue: stage A(cb=0) + B chunk 0 directly, one barrier ----
  for (int i = t; i < 900; i += 256) {
    int p = i >> 2, pl = i & 3;
    short8v v = *(const short8v*)(xb + p * 256 + pl * 8);
    int ph = p / 15, pw = p - 15 * ph;
    *(short8v*)&lsA[(pl * PP + (ph + OFF) * WP + pw + OFF) * 8] = v;
  }
#pragma unroll
  for (int j = 0; j < 3; ++j) {  // KS2 >= 9 so chunk 0 always has 3 planes
    short8v v0 = *(const short8v*)(wbase + (size_t)j * 8192 + t * 8);
    short8v v1 = *(const short8v*)(wbase + (size_t)j * 8192 + 2048 + t * 8);
    *(short8v*)&lsB[0][((j * 4 + (t & 3)) * 128 + (t >> 2)) * 8] = v0;
    *(short8v*)&lsB[0][((j * 4 + (t & 3)) * 128 + 64 + (t >> 2)) * 8] = v1;
  }
  __syncthreads();
  // ---- main loop over flat chunk index ----
  for (int chk = 0; chk < 8 * NCH; ++chk) {
    const int cb = chk / NCH;
    const int c0 = (chk - cb * NCH) * 3;
    const int dn = (KS2 - c0) < 3 ? (KS2 - c0) : 3;
    const int cur = chk & 1;
    const bool hasNext = (chk + 1) < 8 * NCH;
    const int ncb = (chk + 1) / NCH;
    const int nc0 = ((chk + 1) - ncb * NCH) * 3;
    const int ndn = hasNext ? ((KS2 - nc0) < 3 ? (KS2 - nc0) : 3) : 0;
    const bool cross = hasNext && (ncb != cb);
    // issue-early: next chunk's weight loads
    short8v nb0[3], nb1[3];
    if (hasNext) {
      const unsigned short* wn = wbase + ((size_t)ncb * KS2 + nc0) * 8192;
#pragma unroll
      for (int j = 0; j < 3; ++j)
        if (j < ndn) {
          nb0[j] = *(const short8v*)(wn + (size_t)j * 8192 + t * 8);
          nb1[j] = *(const short8v*)(wn + (size_t)j * 8192 + 2048 + t * 8);
        }
    }
    // 48-MFMA cluster (dn==3) between barriers
    auto mfma_d = [&](int dd) {
      const int d = c0 + dd;
      const int kh = d / KS, kw = d - KS * kh;
      const int doff = DIL * (kh * WP + kw);
      const unsigned short* bb = lsB[cur] + dd * 4096;
#pragma unroll
      for (int k16 = 0; k16 < 2; ++k16) {
        const int pl = k16 * 2 + kh8;
        short8v af[2], bfr[4];
#pragma unroll
        for (int mt = 0; mt < 2; ++mt)
          af[mt] = *(const short8v*)&lsA[(pl * PP + rbase[mt] + doff) * 8];
#pragma unroll
        for (int nt = 0; nt < 4; ++nt)
          bfr[nt] = *(const short8v*)&bb[(pl * 128 + nt * 32 + m32) * 8];
#pragma unroll
        for (int mt = 0; mt < 2; ++mt)
#pragma unroll
          for (int nt = 0; nt < 4; ++nt)
            acc[mt][nt] = __builtin_amdgcn_mfma_f32_32x32x16_bf16(
                af[mt], bfr[nt], acc[mt][nt], 0, 0, 0);
      }
    };
    __builtin_amdgcn_s_setprio(1);
    mfma_d(0);
    if (dn == 3) { mfma_d(1); mfma_d(2); }
    __builtin_amdgcn_s_setprio(0);
    // write-late: next chunk into the other buffer
    if (hasNext) {
      unsigned short* bw = lsB[cur ^ 1];
#pragma unroll
      for (int j = 0; j < 3; ++j)
        if (j < ndn) {
          *(short8v*)&bw[((j * 4 + (t & 3)) * 128 + (t >> 2)) * 8] = nb0[j];
          *(short8v*)&bw[((j * 4 + (t & 3)) * 128 + 64 + (t >> 2)) * 8] = nb1[j];
        }
    }
    __syncthreads();
    if (cross) {  // k-block boundary: restage A (8x per kernel, cheap)
      for (int i = t; i < 900; i += 256) {
        int p = i >> 2, pl = i & 3;
        short8v v = *(const short8v*)(xb + p * 256 + ncb * 32 + pl * 8);
        int ph = p / 15, pw = p - 15 * ph;
        *(short8v*)&lsA[(pl * PP + (ph + OFF) * WP + pw + OFF) * 8] = v;
      }
      __syncthreads();
    }
  }
#pragma unroll
  for (int nt = 0; nt < 4; ++nt) {
    int o = nh * 128 + nt * 32 + m32;
    float bv = bias[o];
#pragma unroll
    for (int mt = 0; mt < 2; ++mt) {
#pragma unroll
      for (int r = 0; r < 16; ++r) {
        int pixel = (wv * 2 + mt) * 32 + 8 * (r >> 2) + (r & 3) + 4 * kh8;
        if (pixel < P_)
          dxg[((size_t)(b * P_ + pixel)) * 256 + o] = f2bf(elu1(acc[mt][nt][r] + bv));
      }
    }
  }
}

// ---------------- K-blocked GEMM on [B][P][256] (fusion + scan 1x1) ---------
// A source: bf16 A0 (kb<8) / A1 (kb>=8), or f32 Af (converted during staging).
// modes: 0 = xc = v; 2 = xc = elu(xc+v+bias); 3 = ybf = f2bf(v+bias) + LN sums.
// 8 waves / 512 threads (memory phases need the waves); k-major LDS.
__global__ void __launch_bounds__(512, 4) gemm_kc(
    const unsigned short* __restrict__ A0, const unsigned short* __restrict__ A1,
    const float* __restrict__ Af, int nkb,
    const unsigned short* __restrict__ Bw, const float* __restrict__ bias,
    float* __restrict__ xc, unsigned short* __restrict__ ybf,
    float* __restrict__ stats, int mode) {
  __shared__ __align__(16) unsigned short lsA[4 * P_ * 8];   // [pl][p][8]
  __shared__ __align__(16) unsigned short lsB[4 * 128 * 8];  // [pl][row][8]
  __shared__ float red[16];
  const int b = blockIdx.x, nh = blockIdx.y;
  const int t = threadIdx.x, wv = t >> 6, l = t & 63;
  const int m32 = l & 31, kh8 = l >> 5;
  const int mp = wv & 3, nq = wv >> 2;
  int prow[2];
#pragma unroll
  for (int mt = 0; mt < 2; ++mt) {
    int m = (mp * 2 + mt) * 32 + m32;
    prow[mt] = m < P_ ? m : P_ - 1;
  }
  float16v acc[2][2];
#pragma unroll
  for (int mt = 0; mt < 2; ++mt)
#pragma unroll
    for (int nt = 0; nt < 2; ++nt)
#pragma unroll
      for (int r = 0; r < 16; ++r) acc[mt][nt][r] = 0.f;
  const float* Afb = Af ? Af + (size_t)b * P_ * 256 : nullptr;
  for (int kb = 0; kb < nkb; ++kb) {
    __syncthreads();
    if (Af) {
      for (int i = t; i < 900; i += 512) {
        int p = i >> 2, pl = i & 3;
        const float* src = Afb + (size_t)p * 256 + kb * 32 + pl * 8;
        float4v f0 = *(const float4v*)src;
        float4v f1 = *(const float4v*)(src + 4);
        short8v v;
        v[0] = (short)f2bf(f0[0]); v[1] = (short)f2bf(f0[1]);
        v[2] = (short)f2bf(f0[2]); v[3] = (short)f2bf(f0[3]);
        v[4] = (short)f2bf(f1[0]); v[5] = (short)f2bf(f1[1]);
        v[6] = (short)f2bf(f1[2]); v[7] = (short)f2bf(f1[3]);
        *(short8v*)&lsA[(pl * P_ + p) * 8] = v;
      }
    } else {
      const unsigned short* Asb =
          ((kb & 8) ? A1 : A0) + (size_t)b * P_ * 256;
      for (int i = t; i < 900; i += 512) {
        int p = i >> 2, pl = i & 3;
        short8v v = *(const short8v*)(Asb + (size_t)p * 256 + (kb & 7) * 32 + pl * 8);
        *(short8v*)&lsA[(pl * P_ + p) * 8] = v;
      }
    }
    {
      short8v v = *(const short8v*)(Bw + (size_t)kb * 8192 + nh * 4096 + t * 8);
      *(short8v*)&lsB[((t & 3) * 128 + (t >> 2)) * 8] = v;
    }
    __syncthreads();
#pragma unroll
    for (int k16 = 0; k16 < 2; ++k16) {
      const int pl = k16 * 2 + kh8;
      short8v af[2], bfr[2];
#pragma unroll
      for (int mt = 0; mt < 2; ++mt)
        af[mt] = *(const short8v*)&lsA[(pl * P_ + prow[mt]) * 8];
#pragma unroll
      for (int nt = 0; nt < 2; ++nt)
        bfr[nt] = *(const short8v*)&lsB[(pl * 128 + (nq * 2 + nt) * 32 + m32) * 8];
#pragma unroll
      for (int mt = 0; mt < 2; ++mt)
#pragma unroll
        for (int nt = 0; nt < 2; ++nt)
          acc[mt][nt] = __builtin_amdgcn_mfma_f32_32x32x16_bf16(
              af[mt], bfr[nt], acc[mt][nt], 0, 0, 0);
    }
  }
  float s1 = 0.f, s2 = 0.f;
#pragma unroll
  for (int nt = 0; nt < 2; ++nt) {
    int o = nh * 128 + (nq * 2 + nt) * 32 + m32;
    float bv = bias ? bias[o] : 0.f;
#pragma unroll
    for (int mt = 0; mt < 2; ++mt) {
#pragma unroll
      for (int r = 0; r < 16; ++r) {
        int pixel = (mp * 2 + mt) * 32 + 8 * (r >> 2) + (r & 3) + 4 * kh8;
        if (pixel >= P_) continue;
        size_t idx = ((size_t)(b * P_ + pixel)) * 256 + o;
        float v = acc[mt][nt][r];
        if (mode == 0) {
          xc[idx] = v;
        } else if (mode == 2) {
          xc[idx] = elu1(xc[idx] + v + bv);
        } else {
          v += bv;
          ybf[idx] = f2bf(v);
          s1 += v;
          s2 = fmaf(v, v, s2);
        }
      }
    }
  }
  if (mode == 3) {
#pragma unroll
    for (int off = 32; off; off >>= 1) {
      s1 += __shfl_down(s1, off, 64);
      s2 += __shfl_down(s2, off, 64);
    }
    if (l == 0) { red[wv] = s1; red[8 + wv] = s2; }
    __syncthreads();
    if (t == 0) {
      float a = 0.f, c2 = 0.f;
#pragma unroll
      for (int w = 0; w < 8; ++w) { a += red[w]; c2 += red[8 + w]; }
      stats[nh * 512 + b] = a;
      stats[nh * 512 + 256 + b] = c2;
    }
  }
}

// ---------------- fused LN-apply + ELU + var + threefry update --------------
// Vectorized: 8 consecutive elements per thread per iteration (G13).
__global__ void __launch_bounds__(512) step_fused(
    const unsigned short* __restrict__ ybf, float* __restrict__ xc,
    unsigned short* __restrict__ xcbf, const float* __restrict__ stats,
    const float* __restrict__ lnwT, const float* __restrict__ lnbT,
    const float* __restrict__ sp_a, const float* __restrict__ ss_a,
    const float* __restrict__ rw_a, const float* __restrict__ prob_a,
    int s, uint32_t k0, uint32_t k1, int last, float* __restrict__ vout) {
  __shared__ float red[16];
  const int b = blockIdx.x, t = threadIdx.x;
  const float mean = (stats[b] + stats[512 + b]) * (1.0f / 57600.0f);
  const float var =
      (stats[256 + b] + stats[768 + b]) * (1.0f / 57600.0f) - mean * mean;
  const float rstd = rsqrtf(var + 1e-5f);
  const float sp = sp_a[s], pss = prob_a[s] * ss_a[s], rw1 = 1.0f + rw_a[s];
  float s1 = 0.f, s2 = 0.f;
  const size_t base = (size_t)b * CHW;
  for (int g = t; g < 7200; g += 512) {
    int i0 = g * 8;
    int p = i0 >> 8, c0 = i0 & 255;  // 8-group never crosses a p boundary
    size_t idx = base + i0;
    short8v yv = *(const short8v*)(ybf + idx);
    float4v x0 = *(const float4v*)(xc + idx);
    float4v x1 = *(const float4v*)(xc + idx + 4);
    float4v lw0 = *(const float4v*)(lnwT + i0);
    float4v lw1 = *(const float4v*)(lnwT + i0 + 4);
    float4v lb0 = *(const float4v*)(lnbT + i0);
    float4v lb1 = *(const float4v*)(lnbT + i0 + 4);
    const uint32_t jbase = (uint32_t)b * 57600u + (uint32_t)c0 * 225u + (uint32_t)p;
    float4v o0, o1;
    short8v ob;
#pragma unroll
    for (int e = 0; e < 8; ++e) {
      float y = bf2f((unsigned short)yv[e]);
      float lw = e < 4 ? lw0[e] : lw1[e - 4];
      float lb = e < 4 ? lb0[e] : lb1[e - 4];
      float xo = e < 4 ? x0[e] : x1[e - 4];
      float dx = elu1(fmaf((y - mean) * rstd, lw, lb));
      s1 += dx;
      s2 = fmaf(dx, dx, s2);
      uint32_t y0, y1;
      tf2x32(k0, k1, 0u, jbase + 225u * (uint32_t)e, y0, y1);
      float n = tf_uniform(y0 ^ y1);
      float xn = fmaf(xo, rw1, fmaf(dx, sp, n * pss));
      if (e < 4) o0[e] = xn; else o1[e - 4] = xn;
      ob[e] = (short)f2bf(xn);
    }
    *(float4v*)(xc + idx) = o0;
    *(float4v*)(xc + idx + 4) = o1;
    if (!last) *(short8v*)(xcbf + idx) = ob;
  }
  int wv = t >> 6, l = t & 63;
#pragma unroll
  for (int off = 32; off; off >>= 1) {
    s1 += __shfl_down(s1, off, 64);
    s2 += __shfl_down(s2, off, 64);
  }
  if (l == 0) { red[wv] = s1; red[8 + wv] = s2; }
  __syncthreads();
  if (t == 0) {
    float a = 0.f, c2 = 0.f;
#pragma unroll
    for (int w = 0; w < 8; ++w) { a += red[w]; c2 += red[8 + w]; }
    float mv = a * (1.0f / 57600.0f);
    vout[b * 8 + s] = (c2 - 57600.0f * mv * mv) * (1.0f / 57599.0f);
  }
}

// ---------------- prep + epilogue kernels -----------------------------------
__global__ void __launch_bounds__(256) prep_x(const float* __restrict__ x,
                                              unsigned short* __restrict__ xbf) {
  __shared__ unsigned short ts[64 * 232];
  const int b = blockIdx.x, c0 = blockIdx.y * 64;
  const float* xs = x + ((size_t)b * 256 + c0) * P_;
  for (int i = threadIdx.x; i < 64 * P_; i += 256) {
    int c = i / P_, p = i - P_ * c;
    ts[c * 232 + p] = f2bf(xs[c * P_ + p]);
  }
  __syncthreads();
  for (int i = threadIdx.x; i < 64 * P_; i += 256) {
    int p = i >> 6, c = i & 63;
    xbf[((size_t)b * P_ + p) * 256 + c0 + c] = ts[c * 232 + p];
  }
}

__global__ void wt_prep(const float* __restrict__ w, unsigned short* __restrict__ wt,
                        int ks2) {
  int i = blockIdx.x * 256 + threadIdx.x;
  if (i >= 65536 * ks2) return;
  int cl = i & 31, o = (i >> 5) & 255, cbd = i >> 13;
  int d = cbd % ks2, cb = cbd / ks2;
  wt[i] = f2bf(w[((size_t)(o * 256) + cb * 32 + cl) * ks2 + d]);
}

__global__ void wk_prep(const float* __restrict__ w, unsigned short* __restrict__ wt,
                        int K) {
  int i = blockIdx.x * 256 + threadIdx.x;
  if (i >= K * 256) return;
  int kc = i & 31, o = (i >> 5) & 255, kb = i >> 13;
  wt[i] = f2bf(w[(size_t)o * K + kb * 32 + kc]);
}

__global__ void ln_tr(const float* __restrict__ lw, const float* __restrict__ lb,
                      float* __restrict__ ow, float* __restrict__ ob) {
  int p = blockIdx.x, c = threadIdx.x;
  ow[p * 256 + c] = lw[c * P_ + p];
  ob[p * 256 + c] = lb[c * P_ + p];
}

__global__ void __launch_bounds__(256) final_tr(const float* __restrict__ xc,
                                                float* __restrict__ out) {
  __shared__ float ts[64][226];
  const int b = blockIdx.x, c0 = blockIdx.y * 64;
  for (int i = threadIdx.x; i < 64 * P_; i += 256) {
    int cl = i & 63, p = i >> 6;
    ts[cl][p] = xc[((size_t)(b * P_ + p)) * 256 + c0 + cl];
  }
  __syncthreads();
  for (int i = threadIdx.x; i < 64 * P_; i += 256) {
    int cl = i / P_, p = i - P_ * cl;
    out[((size_t)(b * 256 + c0 + cl)) * P_ + p] = ts[cl][p];
  }
}

// ---------------- launch ----------------------------------------------------
extern "C" void kernel_launch(void* const* d_in, const int* in_sizes, int n_in,
                              void* d_out, int out_size, void* d_ws,
                              size_t ws_size, hipStream_t stream) {
  const float* x = (const float*)d_in[0];
  const float* prob = (const float*)d_in[1];
  const float* w3 = (const float*)d_in[2];
  const float* b3 = (const float*)d_in[3];
  const float* w3d = (const float*)d_in[4];
  const float* b3d = (const float*)d_in[5];
  const float* w5 = (const float*)d_in[6];
  const float* b5 = (const float*)d_in[7];
  const float* w7 = (const float*)d_in[8];
  const float* b7 = (const float*)d_in[9];
  const float* wf = (const float*)d_in[10];
  const float* bfus = (const float*)d_in[11];
  const float* w1 = (const float*)d_in[12];
  const float* b1 = (const float*)d_in[13];
  const float* lnw = (const float*)d_in[14];
  const float* lnb = (const float*)d_in[15];
  const float* sp = (const float*)d_in[16];
  const float* ss = (const float*)d_in[17];
  const float* rw = (const float*)d_in[18];
  float* out = (float*)d_out;

  // ws layout (117,964,800 B):
  //   phase 1 (convs+fusion): dxg0 [0,29.5M) dxg1 [29.5M,59M) xc [59M,118M)
  //   phase 2 (scan):         xcbf [0,29.5M) ybf  [29.5M,59M) xc [59M,118M)
  unsigned short* dxg0 = (unsigned short*)d_ws;
  unsigned short* dxg1 = (unsigned short*)((char*)d_ws + 29491200);
  float* xc = (float*)((char*)d_ws + 58982400);
  unsigned short* xcbf = dxg0;  // reuse after fusion
  unsigned short* ybf = dxg1;   // reuse after fusion

  // d_out[0..59MB) is scratch until final_tr.
  char* sc = (char*)d_out;
  unsigned short* wT3 = (unsigned short*)(sc + 0);
  unsigned short* wT3d = (unsigned short*)(sc + 1179648);
  unsigned short* wT5 = (unsigned short*)(sc + 2359296);
  unsigned short* wT7 = (unsigned short*)(sc + 5636096);
  unsigned short* wfT = (unsigned short*)(sc + 12058624);
  unsigned short* w1T = (unsigned short*)(sc + 12582912);
  float* lnwT = (float*)(sc + 12713984);
  float* lnbT = (float*)(sc + 12944384);
  unsigned short* xbf = (unsigned short*)(sc + 13174784);  // 29.5MB, ends 42.7M
  float* stats = (float*)(sc + 42665984);  // [2 halves][2 sums][256]

  prep_x<<<dim3(B_, 4), 256, 0, stream>>>(x, xbf);
  wt_prep<<<(65536 * 9 + 255) / 256, 256, 0, stream>>>(w3, wT3, 9);
  wt_prep<<<(65536 * 9 + 255) / 256, 256, 0, stream>>>(w3d, wT3d, 9);
  wt_prep<<<(65536 * 25 + 255) / 256, 256, 0, stream>>>(w5, wT5, 25);
  wt_prep<<<(65536 * 49 + 255) / 256, 256, 0, stream>>>(w7, wT7, 49);
  wk_prep<<<1024, 256, 0, stream>>>(wf, wfT, 1024);
  wk_prep<<<256, 256, 0, stream>>>(w1, w1T, 256);
  ln_tr<<<P_, 256, 0, stream>>>(lnw, lnb, lnwT, lnbT);

  // multi-scale perception: pairwise convs + two K=512 fusion GEMMs
  conv_mfma<3, 1, 1><<<dim3(B_, 2), 256, 0, stream>>>(xbf, wT3, b3, dxg0);
  conv_mfma<3, 2, 2><<<dim3(B_, 2), 256, 0, stream>>>(xbf, wT3d, b3d, dxg1);
  gemm_kc<<<dim3(B_, 2), 512, 0, stream>>>(dxg0, dxg1, nullptr, 16, wfT,
                                           nullptr, xc, nullptr, nullptr, 0);
  conv_mfma<5, 1, 2><<<dim3(B_, 2), 256, 0, stream>>>(xbf, wT5, b5, dxg0);
  conv_mfma<7, 1, 3><<<dim3(B_, 2), 256, 0, stream>>>(xbf, wT7, b7, dxg1);
  gemm_kc<<<dim3(B_, 2), 512, 0, stream>>>(dxg0, dxg1, nullptr, 16, wfT + 131072,
                                           bfus, xc, nullptr, nullptr, 2);

  // scan: first 1x1 GEMM stages from f32 xc (converted in staging) to avoid
  // a bf16-copy race; later ones read xcbf written by step_fused.
  gemm_kc<<<dim3(B_, 2), 512, 0, stream>>>(nullptr, nullptr, xc, 8, w1T, b1,
                                           nullptr, ybf, stats, 3);
  for (int si = 0; si < S_; ++si) {
    uint32_t k0s, k1s;
    tf2x32(0u, 42u, 0u, (uint32_t)si, k0s, k1s);  // fold_in(key(42), si)
    step_fused<<<B_, 512, 0, stream>>>(ybf, xc, xcbf, stats, lnwT, lnbT, sp, ss, rw,
                                       prob, si, k0s, k1s, si == S_ - 1, out + NX);
    if (si < S_ - 1)
      gemm_kc<<<dim3(B_, 2), 512, 0, stream>>>(xcbf, xcbf, nullptr, 8, w1T, b1,
                                               nullptr, ybf, stats, 3);
  }

  final_tr<<<dim3(B_, 4), 256, 0, stream>>>(xc, out);
}